// Round 11
// baseline (161.726 us; speedup 1.0000x reference)
//
#include <hip/hip_runtime.h>

#define DMODEL 1024
#define NHEADS 16
#define DHEAD  64
#define RANK   16
#define BATCH  4
#define SEQ    1024
#define MTOT   (BATCH*SEQ)   // 4096
#define QSCALE 0.18033688011112042f  // log2(e)/8 : folded into Q projection

typedef __bf16 bf16;
typedef __bf16 bf16x8 __attribute__((ext_vector_type(8)));
typedef __bf16 bf16x4 __attribute__((ext_vector_type(4)));
typedef float  f32x4  __attribute__((ext_vector_type(4)));

// Byte-offset swizzle for LDS tiles with 128B rows (16B granules).
__device__ __forceinline__ int swz128(int row, int byte_in_row) {
  int slot = byte_in_row >> 4;
  return row * 128 + (((slot ^ (row & 7)) << 4) | (byte_in_row & 15));
}

// async global->LDS, 16B per lane. lds ptr wave-uniform; HW adds lane*16.
__device__ __forceinline__ void gll16(const void* g, void* l) {
  __builtin_amdgcn_global_load_lds((const __attribute__((address_space(1))) unsigned int*)g,
                                   (__attribute__((address_space(3))) unsigned int*)l, 16, 0, 0);
}

// two ds_read_b64_tr_b16 with literal offsets (rule 18 fence applied by caller)
#define TRRD(lo, hi, base, o0, o1)                                   \
  asm volatile("ds_read_b64_tr_b16 %0, %2 offset:" #o0 "\n\t"        \
               "ds_read_b64_tr_b16 %1, %2 offset:" #o1               \
               : "=v"(lo), "=v"(hi) : "v"(base));

// ---------------- Weff = W + 2 * (A@B)^T  (stored [n][k], bf16) -------------
__global__ void prep_weff_kernel(
    const float* __restrict__ W0, const float* __restrict__ A0, const float* __restrict__ B0,
    const float* __restrict__ W1, const float* __restrict__ A1, const float* __restrict__ B1,
    const float* __restrict__ W2, const float* __restrict__ A2, const float* __restrict__ B2,
    const float* __restrict__ W3, const float* __restrict__ A3, const float* __restrict__ B3,
    bf16* __restrict__ out) {
  const int l = blockIdx.y;
  const float* W = l == 0 ? W0 : l == 1 ? W1 : l == 2 ? W2 : W3;
  const float* A = l == 0 ? A0 : l == 1 ? A1 : l == 2 ? A2 : A3;
  const float* Bm = l == 0 ? B0 : l == 1 ? B1 : l == 2 ? B2 : B3;
  out += (size_t)l * DMODEL * DMODEL;
  const int n = blockIdx.x;
  __shared__ float bsc[RANK];
  if (threadIdx.x < RANK) bsc[threadIdx.x] = Bm[threadIdx.x * DMODEL + n] * 2.0f;
  __syncthreads();
  float br[RANK];
#pragma unroll
  for (int r = 0; r < RANK; ++r) br[r] = bsc[r];
  for (int k0 = 0; k0 < DMODEL; k0 += 256) {
    int k = k0 + threadIdx.x;
    float acc = W[n * DMODEL + k];
    const float4* arow = (const float4*)(A + k * RANK);
#pragma unroll
    for (int r4 = 0; r4 < 4; ++r4) {
      float4 a = arow[r4];
      acc += a.x*br[r4*4+0] + a.y*br[r4*4+1] + a.z*br[r4*4+2] + a.w*br[r4*4+3];
    }
    out[n * DMODEL + k] = (bf16)acc;
  }
}

__global__ void cast_x_kernel(const float* __restrict__ x, bf16* __restrict__ xb) {
  int i = (blockIdx.x * blockDim.x + threadIdx.x) * 4;
  float4 v = *(const float4*)(x + i);
  bf16x4 o = { (bf16)v.x, (bf16)v.y, (bf16)v.z, (bf16)v.w };
  *(bf16x4*)(xb + i) = o;
}

// QKV fused over N=3072: 128x256 tile, 8 waves (2x4 grid, 64x64 per wave).
__global__ __launch_bounds__(512) void gemm_qkv_kernel(
    const bf16* __restrict__ xb, const bf16* __restrict__ weff,
    const float* __restrict__ bq, const float* __restrict__ bk, const float* __restrict__ bv,
    bf16* __restrict__ Qb, bf16* __restrict__ Kb, bf16* __restrict__ Vb)
{
  __shared__ __align__(16) char sA[16384];   // 128 rows x 64 bf16
  __shared__ __align__(16) char sB[32768];   // 256 rows x 64 bf16
  const int tid = threadIdx.x, w = tid >> 6, lane = tid & 63;
  const int bid = blockIdx.x;
  const int nb = (bid & 7) * 48 + (bid >> 3);
  const int n0 = (nb % 12) * 256, m0 = (nb / 12) * 128;
  const int z = n0 >> 10;
  const float* bias = z == 0 ? bq : z == 1 ? bk : bv;
  bf16* outp = z == 0 ? Qb : (z == 1 ? Kb : Vb);
  const float scl = z == 0 ? QSCALE : 1.0f;
  const int wm = (w & 1) * 64, wn = (w >> 1) * 64;
  f32x4 acc[4][4] = {};

  const bf16* pA[2]; const bf16* pB[4]; char* lA[2]; char* lB[4];
#pragma unroll
  for (int i = 0; i < 2; ++i) {
    int ci = i * 8 + w;
    int row = ci * 8 + (lane >> 3);
    int ss = (lane & 7) ^ (row & 7);
    pA[i] = xb + (size_t)(m0 + row) * DMODEL + ss * 8;
    lA[i] = sA + ci * 1024;
  }
#pragma unroll
  for (int i = 0; i < 4; ++i) {
    int ci = i * 8 + w;
    int row = ci * 8 + (lane >> 3);
    int ss = (lane & 7) ^ (row & 7);
    pB[i] = weff + (size_t)(n0 + row) * DMODEL + ss * 8;
    lB[i] = sB + ci * 1024;
  }
  for (int kt = 0; kt < DMODEL / 64; ++kt) {
    const int kbase = kt * 64;
#pragma unroll
    for (int i = 0; i < 2; ++i) gll16(pA[i] + kbase, lA[i]);
#pragma unroll
    for (int i = 0; i < 4; ++i) gll16(pB[i] + kbase, lB[i]);
    __syncthreads();
#pragma unroll
    for (int ks = 0; ks < 2; ++ks) {
      bf16x8 af[4], bfg[4];
#pragma unroll
      for (int mi = 0; mi < 4; ++mi)
        af[mi] = *(const bf16x8*)(sA + swz128(wm + mi*16 + (lane & 15), ks*64 + (lane >> 4)*16));
#pragma unroll
      for (int ni = 0; ni < 4; ++ni)
        bfg[ni] = *(const bf16x8*)(sB + swz128(wn + ni*16 + (lane & 15), ks*64 + (lane >> 4)*16));
#pragma unroll
      for (int mi = 0; mi < 4; ++mi)
#pragma unroll
        for (int ni = 0; ni < 4; ++ni)
          acc[mi][ni] = __builtin_amdgcn_mfma_f32_16x16x32_bf16(af[mi], bfg[ni], acc[mi][ni], 0, 0, 0);
    }
    __syncthreads();
  }

#pragma unroll
  for (int mi = 0; mi < 4; ++mi) {
#pragma unroll
    for (int ni = 0; ni < 4; ++ni) {
      int col = n0 + wn + ni * 16 + (lane & 15);
      float bcol = bias[col & 1023];
      int h = (col >> 6) & 15, d = col & 63;
#pragma unroll
      for (int r = 0; r < 4; ++r) {
        int row = m0 + wm + mi * 16 + (lane >> 4) * 4 + r;
        float v = (acc[mi][ni][r] + bcol) * scl;
        int b = row >> 10, s = row & 1023;
        outp[(size_t)((b * NHEADS + h) * SEQ + s) * DHEAD + d] = (bf16)v;
      }
    }
  }
}

// ---- GEMM core 64x128 (4 waves): used by gemm_o ----------------------------
__device__ __forceinline__ void gemm_core64(
    const bf16* __restrict__ Ain, const bf16* __restrict__ Bin,
    char* sA, char* sB, int m0, int n0, f32x4 (&acc)[2][4]) {
  const int tid = threadIdx.x;
  const int w = tid >> 6, lane = tid & 63;
  const int wm = (w & 1) * 32, wn = (w >> 1) * 64;
  const bf16* pA[2]; char* lA[2];
  const bf16* pB[4]; char* lB[4];
#pragma unroll
  for (int i = 0; i < 2; ++i) {
    int chunk = i * 4 + w;
    int row = chunk * 8 + (lane >> 3);
    int ss = (lane & 7) ^ (row & 7);
    pA[i] = Ain + (size_t)(m0 + row) * DMODEL + ss * 8;
    lA[i] = sA + chunk * 1024;
  }
#pragma unroll
  for (int i = 0; i < 4; ++i) {
    int chunk = i * 4 + w;
    int row = chunk * 8 + (lane >> 3);
    int ss = (lane & 7) ^ (row & 7);
    pB[i] = Bin + (size_t)(n0 + row) * DMODEL + ss * 8;
    lB[i] = sB + chunk * 1024;
  }
  for (int kt = 0; kt < DMODEL / 64; ++kt) {
    const int kbase = kt * 64;
#pragma unroll
    for (int i = 0; i < 2; ++i) gll16(pA[i] + kbase, lA[i]);
#pragma unroll
    for (int i = 0; i < 4; ++i) gll16(pB[i] + kbase, lB[i]);
    __syncthreads();
#pragma unroll
    for (int ks = 0; ks < 2; ++ks) {
      bf16x8 af[2], bfg[4];
#pragma unroll
      for (int mi = 0; mi < 2; ++mi)
        af[mi] = *(const bf16x8*)(sA + swz128(wm + mi*16 + (lane & 15), ks*64 + (lane >> 4)*16));
#pragma unroll
      for (int ni = 0; ni < 4; ++ni)
        bfg[ni] = *(const bf16x8*)(sB + swz128(wn + ni*16 + (lane & 15), ks*64 + (lane >> 4)*16));
#pragma unroll
      for (int mi = 0; mi < 2; ++mi)
#pragma unroll
        for (int ni = 0; ni < 4; ++ni)
          acc[mi][ni] = __builtin_amdgcn_mfma_f32_16x16x32_bf16(af[mi], bfg[ni], acc[mi][ni], 0, 0, 0);
    }
    __syncthreads();
  }
}

// O projection + residual -> fp32, tiles 64x128
__global__ __launch_bounds__(256) void gemm_o_kernel(
    const bf16* __restrict__ ctx, const bf16* __restrict__ weff,
    const float* __restrict__ bias, const float* __restrict__ resid,
    float* __restrict__ outf)
{
  __shared__ __align__(16) char sA[8192];
  __shared__ __align__(16) char sB[16384];
  const int tid = threadIdx.x, w = tid >> 6, lane = tid & 63;
  const int bid = blockIdx.x;                        // 512 blocks
  const int nb = (bid & 7) * 64 + (bid >> 3);
  const int n0 = (nb & 7) * 128, m0 = (nb >> 3) * 64;
  const int wm = (w & 1) * 32, wn = (w >> 1) * 64;
  f32x4 acc[2][4] = {};
  gemm_core64(ctx, weff, sA, sB, m0, n0, acc);
#pragma unroll
  for (int mi = 0; mi < 2; ++mi) {
#pragma unroll
    for (int ni = 0; ni < 4; ++ni) {
      int col = n0 + wn + ni * 16 + (lane & 15);
      float bcol = bias[col];
#pragma unroll
      for (int r = 0; r < 4; ++r) {
        int row = m0 + wm + mi * 16 + (lane >> 4) * 4 + r;
        outf[(size_t)row * DMODEL + col] =
            acc[mi][ni][r] + bcol + resid[(size_t)row * DMODEL + col];
      }
    }
  }
}

// -------- flash attention: QBLK=128, 8 waves, K/V LDS double-buffer ---------
__global__ __launch_bounds__(512) void flash_kernel(
    const bf16* __restrict__ Qb, const bf16* __restrict__ Kb, const bf16* __restrict__ Vb,
    bf16* __restrict__ ctx, float* __restrict__ lstat)
{
  __shared__ __align__(16) char sK[2 * 8192];   // dbuf rows=key, cols=d (swizzled)
  __shared__ __align__(16) char sV[2 * 8192];   // dbuf subtiled [k/4][d/16][4][16]
  __shared__ __align__(16) char sP[8 * 2048];   // per-wave P^T [64 key][16 q]
  const int tid = threadIdx.x, w = tid >> 6, lane = tid & 63;
  const int bid = blockIdx.x;
  const int nb = (bid & 7) * 64 + (bid >> 3);
  const int bh = nb >> 3;
  const int q0 = (nb & 7) * 128;
  const bf16* Qbase = Qb + (size_t)bh * SEQ * DHEAD;
  const bf16* Kbase = Kb + (size_t)bh * SEQ * DHEAD;
  const bf16* Vbase = Vb + (size_t)bh * SEQ * DHEAD;
  const int qw = q0 + w * 16;

  bf16x8 aq[2];
#pragma unroll
  for (int ks = 0; ks < 2; ++ks)
    aq[ks] = *(const bf16x8*)(Qbase + (size_t)(qw + (lane & 15)) * DHEAD + ks * 32 + (lane >> 4) * 8);

  const bf16* pK; const bf16* pV; int lKo; int lVo;
  {
    int ci = w;
    int rowK = ci * 8 + (lane >> 3);
    int ssK = (lane & 7) ^ (rowK & 7);
    pK = Kbase + (size_t)rowK * DHEAD + ssK * 8;    // + kt*64*DHEAD
    lKo = ci * 1024;
    int kV = ci * 8 + ((lane >> 5) & 1) * 4 + ((lane >> 1) & 3);
    int dV = (((lane >> 3) & 3) << 4) + ((lane & 1) << 3);
    pV = Vbase + (size_t)kV * DHEAD + dV;           // + kt*64*DHEAD
    lVo = ci * 1024;
  }

  char* sPw = sP + w * 2048;
  const unsigned pbase = (unsigned)(uintptr_t)sPw + ((lane >> 4) << 8) + ((lane & 15) << 3);
  const unsigned vbase0 = (unsigned)(uintptr_t)sV + ((lane >> 4) << 10) + ((lane & 15) << 3);
  char* pwr = sPw + ((lane >> 4) << 3) + (lane & 15) * 32;

  f32x4 cacc[4] = {};
  float lsum[4] = {0.f, 0.f, 0.f, 0.f};

  // prologue: stage k-tile 0 into buffer 0
  gll16(pK, sK + lKo);
  gll16(pV, sV + lVo);
  __syncthreads();

  for (int kt = 0; kt < SEQ / 64; ++kt) {
    const int cur = (kt & 1) << 13, nxt = cur ^ 8192;
    if (kt + 1 < SEQ / 64) {       // prefetch next tile; drains at loop-end barrier
      const size_t kofs = (size_t)((kt + 1) * 64) * DHEAD;
      gll16(pK + kofs, sK + nxt + lKo);
      gll16(pV + kofs, sV + nxt + lVo);
    }

    f32x4 sc[4] = {};
    __builtin_amdgcn_s_setprio(1);
#pragma unroll
    for (int ks = 0; ks < 2; ++ks)
#pragma unroll
      for (int ni = 0; ni < 4; ++ni) {
        bf16x8 bk = *(const bf16x8*)(sK + cur + swz128(ni*16 + (lane & 15), ks*64 + (lane >> 4)*16));
        sc[ni] = __builtin_amdgcn_mfma_f32_16x16x32_bf16(aq[ks], bk, sc[ni], 0, 0, 0);
      }
    __builtin_amdgcn_s_setprio(0);

    // P = exp2(sc); accumulate row partial sums; write P^T [key][q]
#pragma unroll
    for (int ni = 0; ni < 4; ++ni) {
      float p0 = __builtin_amdgcn_exp2f(sc[ni][0]);
      float p1 = __builtin_amdgcn_exp2f(sc[ni][1]);
      float p2 = __builtin_amdgcn_exp2f(sc[ni][2]);
      float p3 = __builtin_amdgcn_exp2f(sc[ni][3]);
      lsum[0] += p0; lsum[1] += p1; lsum[2] += p2; lsum[3] += p3;
      bf16x4 pb = { (bf16)p0, (bf16)p1, (bf16)p2, (bf16)p3 };
      *(bf16x4*)(pwr + ni * 512) = pb;   // key=ni*16+(lane&15) -> *32B
    }
    asm volatile("s_waitcnt lgkmcnt(0)" ::: "memory");

    unsigned long long t0, t1, v0[4], v1[4];
    const unsigned vb = vbase0 + cur;
    // ks = 0
    TRRD(t0, t1, pbase, 0, 128)
    TRRD(v0[0], v1[0], vb, 0, 512)
    TRRD(v0[1], v1[1], vb, 128, 640)
    TRRD(v0[2], v1[2], vb, 256, 768)
    TRRD(v0[3], v1[3], vb, 384, 896)
    asm volatile("s_waitcnt lgkmcnt(0)" ::: "memory");
    __builtin_amdgcn_sched_barrier(0);
    {
      union { unsigned long long u[2]; bf16x8 v; } pu, vu;
      pu.u[0] = t0; pu.u[1] = t1;
      __builtin_amdgcn_s_setprio(1);
#pragma unroll
      for (int ni = 0; ni < 4; ++ni) {
        vu.u[0] = v0[ni]; vu.u[1] = v1[ni];
        cacc[ni] = __builtin_amdgcn_mfma_f32_16x16x32_bf16(pu.v, vu.v, cacc[ni], 0, 0, 0);
      }
      __builtin_amdgcn_s_setprio(0);
    }
    // ks = 1
    TRRD(t0, t1, pbase, 1024, 1152)
    TRRD(v0[0], v1[0], vb, 4096, 4608)
    TRRD(v0[1], v1[1], vb, 4224, 4736)
    TRRD(v0[2], v1[2], vb, 4352, 4864)
    TRRD(v0[3], v1[3], vb, 4480, 4992)
    asm volatile("s_waitcnt lgkmcnt(0)" ::: "memory");
    __builtin_amdgcn_sched_barrier(0);
    {
      union { unsigned long long u[2]; bf16x8 v; } pu, vu;
      pu.u[0] = t0; pu.u[1] = t1;
      __builtin_amdgcn_s_setprio(1);
#pragma unroll
      for (int ni = 0; ni < 4; ++ni) {
        vu.u[0] = v0[ni]; vu.u[1] = v1[ni];
        cacc[ni] = __builtin_amdgcn_mfma_f32_16x16x32_bf16(pu.v, vu.v, cacc[ni], 0, 0, 0);
      }
      __builtin_amdgcn_s_setprio(0);
    }
    __syncthreads();   // drains prefetch vmcnt + publishes next buffer
  }

  // one deferred row-sum reduce over the 16-lane group
#pragma unroll
  for (int r = 0; r < 4; ++r) {
#pragma unroll
    for (int off = 1; off < 16; off <<= 1) lsum[r] += __shfl_xor(lsum[r], off);
  }

  const int b = bh >> 4, hh = bh & 15;
#pragma unroll
  for (int r = 0; r < 4; ++r) {
    float inv = __builtin_amdgcn_rcpf(lsum[r]);
    int qrow = qw + (lane >> 4) * 4 + r;
#pragma unroll
    for (int ni = 0; ni < 4; ++ni) {
      int d = ni * 16 + (lane & 15);
      ctx[(size_t)(b * SEQ + qrow) * DMODEL + hh * DHEAD + d] = (bf16)(cacc[ni][r] * inv);
    }
    if ((lane & 15) == 0) lstat[(size_t)bh * SEQ + qrow] = lsum[r];
  }
}

// --- attn.mean over heads: direct-global fragments, no LDS, no barriers -----
// Wave owns 32q x 64k; K-fragments reused across the 2 q-subtiles (2x).
// All K/Q fragment reads hit L2 (per-XCD working set ~4MB under the swizzle).
__global__ __launch_bounds__(256) void mean_kernel(
    const bf16* __restrict__ Qb, const bf16* __restrict__ Kb,
    const float* __restrict__ lstat, float* __restrict__ out2)
{
  const int tid = threadIdx.x, w = tid >> 6, lane = tid & 63;
  const int bid = blockIdx.x;                    // 512 blocks x 4 waves
  const int nb = (bid & 7) * 64 + (bid >> 3);    // XCD-chunked (bijective)
  const int b = nb >> 7;                         // 128 blocks per b
  const int nb2 = nb & 127;
  const int q0 = (nb2 >> 4) * 128, k0 = (nb2 & 15) * 64;
  const int qw = q0 + w * 32;                    // wave owns 32 q-rows
  const bf16* Qb_b = Qb + (size_t)b * NHEADS * SEQ * DHEAD;
  const bf16* Kb_b = Kb + (size_t)b * NHEADS * SEQ * DHEAD;
  const float* ls_b = lstat + (size_t)b * NHEADS * SEQ;

  f32x4 macc[2][4] = {};
  for (int h = 0; h < NHEADS; ++h) {
    const bf16* Qbase = Qb_b + (size_t)h * SEQ * DHEAD;
    const bf16* Kbase = Kb_b + (size_t)h * SEQ * DHEAD;
    bf16x8 aq[2][2];
#pragma unroll
    for (int mi = 0; mi < 2; ++mi)
#pragma unroll
      for (int ks = 0; ks < 2; ++ks)
        aq[mi][ks] = *(const bf16x8*)(Qbase + (size_t)(qw + mi*16 + (lane & 15)) * DHEAD
                                      + ks * 32 + (lane >> 4) * 8);
    f32x4 sc[2][4] = {};
#pragma unroll
    for (int ks = 0; ks < 2; ++ks)
#pragma unroll
      for (int ni = 0; ni < 4; ++ni) {
        bf16x8 bk = *(const bf16x8*)(Kbase + (size_t)(k0 + ni*16 + (lane & 15)) * DHEAD
                                     + ks * 32 + (lane >> 4) * 8);
#pragma unroll
        for (int mi = 0; mi < 2; ++mi)
          sc[mi][ni] = __builtin_amdgcn_mfma_f32_16x16x32_bf16(aq[mi][ks], bk, sc[mi][ni], 0, 0, 0);
      }
    const float* ls = ls_b + (size_t)h * SEQ;
    float lsc[2][4];
#pragma unroll
    for (int mi = 0; mi < 2; ++mi)
#pragma unroll
      for (int r = 0; r < 4; ++r)
        lsc[mi][r] = 0.0625f * __builtin_amdgcn_rcpf(ls[qw + mi*16 + (lane >> 4)*4 + r]);
#pragma unroll
    for (int mi = 0; mi < 2; ++mi)
#pragma unroll
      for (int ni = 0; ni < 4; ++ni)
#pragma unroll
        for (int r = 0; r < 4; ++r)
          macc[mi][ni][r] += __builtin_amdgcn_exp2f(sc[mi][ni][r]) * lsc[mi][r];
  }
#pragma unroll
  for (int mi = 0; mi < 2; ++mi)
#pragma unroll
    for (int r = 0; r < 4; ++r) {
      int qrow = qw + mi*16 + (lane >> 4) * 4 + r;
#pragma unroll
      for (int ni = 0; ni < 4; ++ni)
        out2[(size_t)(b * SEQ + qrow) * SEQ + k0 + ni * 16 + (lane & 15)] = macc[mi][ni][r];
    }
}

// ---------------- residual LayerNorm (in-place on fp32 rows) ----------------
__global__ __launch_bounds__(256) void ln_kernel(
    float* __restrict__ hb, const float* __restrict__ g,
    const float* __restrict__ bvec, float* __restrict__ out)
{
  const int row = blockIdx.x, t = threadIdx.x;
  float4 v = *(const float4*)(hb + (size_t)row * DMODEL + t * 4);
  float s = v.x + v.y + v.z + v.w;
  float s2 = v.x*v.x + v.y*v.y + v.z*v.z + v.w*v.w;
#pragma unroll
  for (int off = 32; off >= 1; off >>= 1) {
    s  += __shfl_down(s, off);
    s2 += __shfl_down(s2, off);
  }
  __shared__ float red[8];
  const int w = t >> 6;
  if ((t & 63) == 0) { red[w] = s; red[4 + w] = s2; }
  __syncthreads();
  if (t == 0) {
    red[0] = red[0] + red[1] + red[2] + red[3];
    red[4] = red[4] + red[5] + red[6] + red[7];
  }
  __syncthreads();
  float mu = red[0] * (1.0f / DMODEL);
  float var = red[4] * (1.0f / DMODEL) - mu * mu;
  float rs = rsqrtf(var + 1e-5f);
  float4 gv = *(const float4*)(g + t * 4);
  float4 bv = *(const float4*)(bvec + t * 4);
  float4 o;
  o.x = (v.x - mu) * rs * gv.x + bv.x;
  o.y = (v.y - mu) * rs * gv.y + bv.y;
  o.z = (v.z - mu) * rs * gv.z + bv.z;
  o.w = (v.w - mu) * rs * gv.w + bv.w;
  *(float4*)(out + (size_t)row * DMODEL + t * 4) = o;
}

extern "C" void kernel_launch(void* const* d_in, const int* in_sizes, int n_in,
                              void* d_out, int out_size, void* d_ws, size_t ws_size,
                              hipStream_t stream) {
  (void)in_sizes; (void)n_in; (void)out_size; (void)ws_size;
  const float* x = (const float*)d_in[0];
  const float* w_[4]  = {(const float*)d_in[1],  (const float*)d_in[5],
                         (const float*)d_in[9],  (const float*)d_in[13]};
  const float* b_[4]  = {(const float*)d_in[2],  (const float*)d_in[6],
                         (const float*)d_in[10], (const float*)d_in[14]};
  const float* A_[4]  = {(const float*)d_in[3],  (const float*)d_in[7],
                         (const float*)d_in[11], (const float*)d_in[15]};
  const float* Bm_[4] = {(const float*)d_in[4],  (const float*)d_in[8],
                         (const float*)d_in[12], (const float*)d_in[16]};
  const float* lng = (const float*)d_in[17];
  const float* lnb = (const float*)d_in[18];

  char* ws = (char*)d_ws;
  bf16* xb    = (bf16*)(ws);                         // 8MB, reused as ctx later
  bf16* weff  = (bf16*)(ws + (8u  << 20));           // 4 x 2MB (q|k|v|o contiguous)
  bf16* Qb    = (bf16*)(ws + (16u << 20));           // 8MB [b][h][s][d] (pre-scaled)
  bf16* Kb    = (bf16*)(ws + (24u << 20));           // 8MB [b][h][s][d]
  bf16* Vb    = (bf16*)(ws + (32u << 20));           // 8MB [b][h][s][d]
  float* lstat = (float*)(ws + (40u << 20));         // 256KB
  bf16* ctx = xb;                    // alias: xb dead after QKV projections
  float* hbuf = (float*)d_out;       // fp32 scratch = output slot 0 (in-place LN)
  float* out2 = (float*)d_out + (size_t)MTOT * DMODEL;

  prep_weff_kernel<<<dim3(DMODEL, 4), dim3(256), 0, stream>>>(
      w_[0], A_[0], Bm_[0], w_[1], A_[1], Bm_[1],
      w_[2], A_[2], Bm_[2], w_[3], A_[3], Bm_[3], weff);
  cast_x_kernel<<<dim3(MTOT * DMODEL / 1024), dim3(256), 0, stream>>>(x, xb);

  gemm_qkv_kernel<<<dim3(384), 512, 0, stream>>>(
      xb, weff, b_[0], b_[1], b_[2], Qb, Kb, Vb);

  flash_kernel<<<dim3(512), 512, 0, stream>>>(Qb, Kb, Vb, ctx, lstat);
  mean_kernel<<<dim3(512), 256, 0, stream>>>(Qb, Kb, lstat, out2);
  gemm_o_kernel<<<dim3(512), 256, 0, stream>>>(
      ctx, weff + 3u * DMODEL * DMODEL, b_[3], x, hbuf);
  ln_kernel<<<dim3(MTOT), 256, 0, stream>>>(hbuf, lng, lnb, hbuf);
}

// Round 12
// 134.710 us; speedup vs baseline: 1.2005x; 1.2005x over previous
//
#include <hip/hip_runtime.h>

#define DMODEL 1024
#define NHEADS 16
#define DHEAD  64
#define RANK   16
#define BATCH  4
#define SEQ    1024
#define MTOT   (BATCH*SEQ)   // 4096
#define QSCALE 0.18033688011112042f  // log2(e)/8 : folded into Q projection

typedef __bf16 bf16;
typedef __bf16 bf16x8 __attribute__((ext_vector_type(8)));
typedef __bf16 bf16x4 __attribute__((ext_vector_type(4)));
typedef float  f32x4  __attribute__((ext_vector_type(4)));

// Byte-offset swizzle for LDS tiles with 128B rows (16B granules).
__device__ __forceinline__ int swz128(int row, int byte_in_row) {
  int slot = byte_in_row >> 4;
  return row * 128 + (((slot ^ (row & 7)) << 4) | (byte_in_row & 15));
}

// async global->LDS, 16B per lane. lds ptr wave-uniform; HW adds lane*16.
__device__ __forceinline__ void gll16(const void* g, void* l) {
  __builtin_amdgcn_global_load_lds((const __attribute__((address_space(1))) unsigned int*)g,
                                   (__attribute__((address_space(3))) unsigned int*)l, 16, 0, 0);
}

// two ds_read_b64_tr_b16 with literal offsets (rule 18 fence applied by caller)
#define TRRD(lo, hi, base, o0, o1)                                   \
  asm volatile("ds_read_b64_tr_b16 %0, %2 offset:" #o0 "\n\t"        \
               "ds_read_b64_tr_b16 %1, %2 offset:" #o1               \
               : "=v"(lo), "=v"(hi) : "v"(base));

// ---------------- Weff = W + 2 * (A@B)^T  (stored [n][k], bf16) -------------
__global__ void prep_weff_kernel(
    const float* __restrict__ W0, const float* __restrict__ A0, const float* __restrict__ B0,
    const float* __restrict__ W1, const float* __restrict__ A1, const float* __restrict__ B1,
    const float* __restrict__ W2, const float* __restrict__ A2, const float* __restrict__ B2,
    const float* __restrict__ W3, const float* __restrict__ A3, const float* __restrict__ B3,
    bf16* __restrict__ out) {
  const int l = blockIdx.y;
  const float* W = l == 0 ? W0 : l == 1 ? W1 : l == 2 ? W2 : W3;
  const float* A = l == 0 ? A0 : l == 1 ? A1 : l == 2 ? A2 : A3;
  const float* Bm = l == 0 ? B0 : l == 1 ? B1 : l == 2 ? B2 : B3;
  out += (size_t)l * DMODEL * DMODEL;
  const int n = blockIdx.x;
  __shared__ float bsc[RANK];
  if (threadIdx.x < RANK) bsc[threadIdx.x] = Bm[threadIdx.x * DMODEL + n] * 2.0f;
  __syncthreads();
  float br[RANK];
#pragma unroll
  for (int r = 0; r < RANK; ++r) br[r] = bsc[r];
  for (int k0 = 0; k0 < DMODEL; k0 += 256) {
    int k = k0 + threadIdx.x;
    float acc = W[n * DMODEL + k];
    const float4* arow = (const float4*)(A + k * RANK);
#pragma unroll
    for (int r4 = 0; r4 < 4; ++r4) {
      float4 a = arow[r4];
      acc += a.x*br[r4*4+0] + a.y*br[r4*4+1] + a.z*br[r4*4+2] + a.w*br[r4*4+3];
    }
    out[n * DMODEL + k] = (bf16)acc;
  }
}

__global__ void cast_x_kernel(const float* __restrict__ x, bf16* __restrict__ xb) {
  int i = (blockIdx.x * blockDim.x + threadIdx.x) * 4;
  float4 v = *(const float4*)(x + i);
  bf16x4 o = { (bf16)v.x, (bf16)v.y, (bf16)v.z, (bf16)v.w };
  *(bf16x4*)(xb + i) = o;
}

// QKV fused over N=3072: 128x256 tile, 8 waves (2x4 grid, 64x64 per wave).
__global__ __launch_bounds__(512) void gemm_qkv_kernel(
    const bf16* __restrict__ xb, const bf16* __restrict__ weff,
    const float* __restrict__ bq, const float* __restrict__ bk, const float* __restrict__ bv,
    bf16* __restrict__ Qb, bf16* __restrict__ Kb, bf16* __restrict__ Vb)
{
  __shared__ __align__(16) char sA[16384];   // 128 rows x 64 bf16
  __shared__ __align__(16) char sB[32768];   // 256 rows x 64 bf16
  const int tid = threadIdx.x, w = tid >> 6, lane = tid & 63;
  const int bid = blockIdx.x;
  const int nb = (bid & 7) * 48 + (bid >> 3);
  const int n0 = (nb % 12) * 256, m0 = (nb / 12) * 128;
  const int z = n0 >> 10;
  const float* bias = z == 0 ? bq : z == 1 ? bk : bv;
  bf16* outp = z == 0 ? Qb : (z == 1 ? Kb : Vb);
  const float scl = z == 0 ? QSCALE : 1.0f;
  const int wm = (w & 1) * 64, wn = (w >> 1) * 64;
  f32x4 acc[4][4] = {};

  const bf16* pA[2]; const bf16* pB[4]; char* lA[2]; char* lB[4];
#pragma unroll
  for (int i = 0; i < 2; ++i) {
    int ci = i * 8 + w;
    int row = ci * 8 + (lane >> 3);
    int ss = (lane & 7) ^ (row & 7);
    pA[i] = xb + (size_t)(m0 + row) * DMODEL + ss * 8;
    lA[i] = sA + ci * 1024;
  }
#pragma unroll
  for (int i = 0; i < 4; ++i) {
    int ci = i * 8 + w;
    int row = ci * 8 + (lane >> 3);
    int ss = (lane & 7) ^ (row & 7);
    pB[i] = weff + (size_t)(n0 + row) * DMODEL + ss * 8;
    lB[i] = sB + ci * 1024;
  }
  for (int kt = 0; kt < DMODEL / 64; ++kt) {
    const int kbase = kt * 64;
#pragma unroll
    for (int i = 0; i < 2; ++i) gll16(pA[i] + kbase, lA[i]);
#pragma unroll
    for (int i = 0; i < 4; ++i) gll16(pB[i] + kbase, lB[i]);
    __syncthreads();
#pragma unroll
    for (int ks = 0; ks < 2; ++ks) {
      bf16x8 af[4], bfg[4];
#pragma unroll
      for (int mi = 0; mi < 4; ++mi)
        af[mi] = *(const bf16x8*)(sA + swz128(wm + mi*16 + (lane & 15), ks*64 + (lane >> 4)*16));
#pragma unroll
      for (int ni = 0; ni < 4; ++ni)
        bfg[ni] = *(const bf16x8*)(sB + swz128(wn + ni*16 + (lane & 15), ks*64 + (lane >> 4)*16));
#pragma unroll
      for (int mi = 0; mi < 4; ++mi)
#pragma unroll
        for (int ni = 0; ni < 4; ++ni)
          acc[mi][ni] = __builtin_amdgcn_mfma_f32_16x16x32_bf16(af[mi], bfg[ni], acc[mi][ni], 0, 0, 0);
    }
    __syncthreads();
  }

#pragma unroll
  for (int mi = 0; mi < 4; ++mi) {
#pragma unroll
    for (int ni = 0; ni < 4; ++ni) {
      int col = n0 + wn + ni * 16 + (lane & 15);
      float bcol = bias[col & 1023];
      int h = (col >> 6) & 15, d = col & 63;
#pragma unroll
      for (int r = 0; r < 4; ++r) {
        int row = m0 + wm + mi * 16 + (lane >> 4) * 4 + r;
        float v = (acc[mi][ni][r] + bcol) * scl;
        int b = row >> 10, s = row & 1023;
        outp[(size_t)((b * NHEADS + h) * SEQ + s) * DHEAD + d] = (bf16)v;
      }
    }
  }
}

// ---- GEMM core 64x128 (4 waves): used by gemm_o ----------------------------
__device__ __forceinline__ void gemm_core64(
    const bf16* __restrict__ Ain, const bf16* __restrict__ Bin,
    char* sA, char* sB, int m0, int n0, f32x4 (&acc)[2][4]) {
  const int tid = threadIdx.x;
  const int w = tid >> 6, lane = tid & 63;
  const int wm = (w & 1) * 32, wn = (w >> 1) * 64;
  const bf16* pA[2]; char* lA[2];
  const bf16* pB[4]; char* lB[4];
#pragma unroll
  for (int i = 0; i < 2; ++i) {
    int chunk = i * 4 + w;
    int row = chunk * 8 + (lane >> 3);
    int ss = (lane & 7) ^ (row & 7);
    pA[i] = Ain + (size_t)(m0 + row) * DMODEL + ss * 8;
    lA[i] = sA + chunk * 1024;
  }
#pragma unroll
  for (int i = 0; i < 4; ++i) {
    int chunk = i * 4 + w;
    int row = chunk * 8 + (lane >> 3);
    int ss = (lane & 7) ^ (row & 7);
    pB[i] = Bin + (size_t)(n0 + row) * DMODEL + ss * 8;
    lB[i] = sB + chunk * 1024;
  }
  for (int kt = 0; kt < DMODEL / 64; ++kt) {
    const int kbase = kt * 64;
#pragma unroll
    for (int i = 0; i < 2; ++i) gll16(pA[i] + kbase, lA[i]);
#pragma unroll
    for (int i = 0; i < 4; ++i) gll16(pB[i] + kbase, lB[i]);
    __syncthreads();
#pragma unroll
    for (int ks = 0; ks < 2; ++ks) {
      bf16x8 af[2], bfg[4];
#pragma unroll
      for (int mi = 0; mi < 2; ++mi)
        af[mi] = *(const bf16x8*)(sA + swz128(wm + mi*16 + (lane & 15), ks*64 + (lane >> 4)*16));
#pragma unroll
      for (int ni = 0; ni < 4; ++ni)
        bfg[ni] = *(const bf16x8*)(sB + swz128(wn + ni*16 + (lane & 15), ks*64 + (lane >> 4)*16));
#pragma unroll
      for (int mi = 0; mi < 2; ++mi)
#pragma unroll
        for (int ni = 0; ni < 4; ++ni)
          acc[mi][ni] = __builtin_amdgcn_mfma_f32_16x16x32_bf16(af[mi], bfg[ni], acc[mi][ni], 0, 0, 0);
    }
    __syncthreads();
  }
}

// O projection + residual -> fp32, tiles 64x128
__global__ __launch_bounds__(256) void gemm_o_kernel(
    const bf16* __restrict__ ctx, const bf16* __restrict__ weff,
    const float* __restrict__ bias, const float* __restrict__ resid,
    float* __restrict__ outf)
{
  __shared__ __align__(16) char sA[8192];
  __shared__ __align__(16) char sB[16384];
  const int tid = threadIdx.x, w = tid >> 6, lane = tid & 63;
  const int bid = blockIdx.x;                        // 512 blocks
  const int nb = (bid & 7) * 64 + (bid >> 3);
  const int n0 = (nb & 7) * 128, m0 = (nb >> 3) * 64;
  const int wm = (w & 1) * 32, wn = (w >> 1) * 64;
  f32x4 acc[2][4] = {};
  gemm_core64(ctx, weff, sA, sB, m0, n0, acc);
#pragma unroll
  for (int mi = 0; mi < 2; ++mi) {
#pragma unroll
    for (int ni = 0; ni < 4; ++ni) {
      int col = n0 + wn + ni * 16 + (lane & 15);
      float bcol = bias[col];
#pragma unroll
      for (int r = 0; r < 4; ++r) {
        int row = m0 + wm + mi * 16 + (lane >> 4) * 4 + r;
        outf[(size_t)row * DMODEL + col] =
            acc[mi][ni][r] + bcol + resid[(size_t)row * DMODEL + col];
      }
    }
  }
}

// -------- flash attention: QBLK=128, 8 waves, K/V LDS double-buffer ---------
__global__ __launch_bounds__(512) void flash_kernel(
    const bf16* __restrict__ Qb, const bf16* __restrict__ Kb, const bf16* __restrict__ Vb,
    bf16* __restrict__ ctx, float* __restrict__ lstat)
{
  __shared__ __align__(16) char sK[2 * 8192];   // dbuf rows=key, cols=d (swizzled)
  __shared__ __align__(16) char sV[2 * 8192];   // dbuf subtiled [k/4][d/16][4][16]
  __shared__ __align__(16) char sP[8 * 2048];   // per-wave P^T [64 key][16 q]
  const int tid = threadIdx.x, w = tid >> 6, lane = tid & 63;
  const int bid = blockIdx.x;
  const int nb = (bid & 7) * 64 + (bid >> 3);
  const int bh = nb >> 3;
  const int q0 = (nb & 7) * 128;
  const bf16* Qbase = Qb + (size_t)bh * SEQ * DHEAD;
  const bf16* Kbase = Kb + (size_t)bh * SEQ * DHEAD;
  const bf16* Vbase = Vb + (size_t)bh * SEQ * DHEAD;
  const int qw = q0 + w * 16;

  bf16x8 aq[2];
#pragma unroll
  for (int ks = 0; ks < 2; ++ks)
    aq[ks] = *(const bf16x8*)(Qbase + (size_t)(qw + (lane & 15)) * DHEAD + ks * 32 + (lane >> 4) * 8);

  const bf16* pK; const bf16* pV; int lKo; int lVo;
  {
    int ci = w;
    int rowK = ci * 8 + (lane >> 3);
    int ssK = (lane & 7) ^ (rowK & 7);
    pK = Kbase + (size_t)rowK * DHEAD + ssK * 8;    // + kt*64*DHEAD
    lKo = ci * 1024;
    int kV = ci * 8 + ((lane >> 5) & 1) * 4 + ((lane >> 1) & 3);
    int dV = (((lane >> 3) & 3) << 4) + ((lane & 1) << 3);
    pV = Vbase + (size_t)kV * DHEAD + dV;           // + kt*64*DHEAD
    lVo = ci * 1024;
  }

  char* sPw = sP + w * 2048;
  const unsigned pbase = (unsigned)(uintptr_t)sPw + ((lane >> 4) << 8) + ((lane & 15) << 3);
  const unsigned vbase0 = (unsigned)(uintptr_t)sV + ((lane >> 4) << 10) + ((lane & 15) << 3);
  char* pwr = sPw + ((lane >> 4) << 3) + (lane & 15) * 32;

  f32x4 cacc[4] = {};
  float lsum[4] = {0.f, 0.f, 0.f, 0.f};

  // prologue: stage k-tile 0 into buffer 0
  gll16(pK, sK + lKo);
  gll16(pV, sV + lVo);
  __syncthreads();

  for (int kt = 0; kt < SEQ / 64; ++kt) {
    const int cur = (kt & 1) << 13, nxt = cur ^ 8192;
    if (kt + 1 < SEQ / 64) {       // prefetch next tile; drains at loop-end barrier
      const size_t kofs = (size_t)((kt + 1) * 64) * DHEAD;
      gll16(pK + kofs, sK + nxt + lKo);
      gll16(pV + kofs, sV + nxt + lVo);
    }

    f32x4 sc[4] = {};
    __builtin_amdgcn_s_setprio(1);
#pragma unroll
    for (int ks = 0; ks < 2; ++ks)
#pragma unroll
      for (int ni = 0; ni < 4; ++ni) {
        bf16x8 bk = *(const bf16x8*)(sK + cur + swz128(ni*16 + (lane & 15), ks*64 + (lane >> 4)*16));
        sc[ni] = __builtin_amdgcn_mfma_f32_16x16x32_bf16(aq[ks], bk, sc[ni], 0, 0, 0);
      }
    __builtin_amdgcn_s_setprio(0);

    // P = exp2(sc); accumulate row partial sums; write P^T [key][q]
#pragma unroll
    for (int ni = 0; ni < 4; ++ni) {
      float p0 = __builtin_amdgcn_exp2f(sc[ni][0]);
      float p1 = __builtin_amdgcn_exp2f(sc[ni][1]);
      float p2 = __builtin_amdgcn_exp2f(sc[ni][2]);
      float p3 = __builtin_amdgcn_exp2f(sc[ni][3]);
      lsum[0] += p0; lsum[1] += p1; lsum[2] += p2; lsum[3] += p3;
      bf16x4 pb = { (bf16)p0, (bf16)p1, (bf16)p2, (bf16)p3 };
      *(bf16x4*)(pwr + ni * 512) = pb;   // key=ni*16+(lane&15) -> *32B
    }
    asm volatile("s_waitcnt lgkmcnt(0)" ::: "memory");

    unsigned long long t0, t1, v0[4], v1[4];
    const unsigned vb = vbase0 + cur;
    // ks = 0
    TRRD(t0, t1, pbase, 0, 128)
    TRRD(v0[0], v1[0], vb, 0, 512)
    TRRD(v0[1], v1[1], vb, 128, 640)
    TRRD(v0[2], v1[2], vb, 256, 768)
    TRRD(v0[3], v1[3], vb, 384, 896)
    asm volatile("s_waitcnt lgkmcnt(0)" ::: "memory");
    __builtin_amdgcn_sched_barrier(0);
    {
      union { unsigned long long u[2]; bf16x8 v; } pu, vu;
      pu.u[0] = t0; pu.u[1] = t1;
      __builtin_amdgcn_s_setprio(1);
#pragma unroll
      for (int ni = 0; ni < 4; ++ni) {
        vu.u[0] = v0[ni]; vu.u[1] = v1[ni];
        cacc[ni] = __builtin_amdgcn_mfma_f32_16x16x32_bf16(pu.v, vu.v, cacc[ni], 0, 0, 0);
      }
      __builtin_amdgcn_s_setprio(0);
    }
    // ks = 1
    TRRD(t0, t1, pbase, 1024, 1152)
    TRRD(v0[0], v1[0], vb, 4096, 4608)
    TRRD(v0[1], v1[1], vb, 4224, 4736)
    TRRD(v0[2], v1[2], vb, 4352, 4864)
    TRRD(v0[3], v1[3], vb, 4480, 4992)
    asm volatile("s_waitcnt lgkmcnt(0)" ::: "memory");
    __builtin_amdgcn_sched_barrier(0);
    {
      union { unsigned long long u[2]; bf16x8 v; } pu, vu;
      pu.u[0] = t0; pu.u[1] = t1;
      __builtin_amdgcn_s_setprio(1);
#pragma unroll
      for (int ni = 0; ni < 4; ++ni) {
        vu.u[0] = v0[ni]; vu.u[1] = v1[ni];
        cacc[ni] = __builtin_amdgcn_mfma_f32_16x16x32_bf16(pu.v, vu.v, cacc[ni], 0, 0, 0);
      }
      __builtin_amdgcn_s_setprio(0);
    }
    __syncthreads();   // drains prefetch vmcnt + publishes next buffer
  }

  // one deferred row-sum reduce over the 16-lane group
#pragma unroll
  for (int r = 0; r < 4; ++r) {
#pragma unroll
    for (int off = 1; off < 16; off <<= 1) lsum[r] += __shfl_xor(lsum[r], off);
  }

  const int b = bh >> 4, hh = bh & 15;
#pragma unroll
  for (int r = 0; r < 4; ++r) {
    float inv = __builtin_amdgcn_rcpf(lsum[r]);
    int qrow = qw + (lane >> 4) * 4 + r;
#pragma unroll
    for (int ni = 0; ni < 4; ++ni) {
      int d = ni * 16 + (lane & 15);
      ctx[(size_t)(b * SEQ + qrow) * DMODEL + hh * DHEAD + d] = (bf16)(cacc[ni][r] * inv);
    }
    if ((lane & 15) == 0) lstat[(size_t)bh * SEQ + qrow] = lsum[r];
  }
}

// --- attn.mean over heads: recompute scores, 64(q)x128(k) tile, head-dbuf ---
__global__ __launch_bounds__(256) void mean_kernel(
    const bf16* __restrict__ Qb, const bf16* __restrict__ Kb,
    const float* __restrict__ lstat, float* __restrict__ out2)
{
  __shared__ __align__(16) char sK[2 * 16384];   // dbuf K-tile: 128 rows x 128B
  const int tid = threadIdx.x, w = tid >> 6, lane = tid & 63;
  const int bid = blockIdx.x;                    // 512 blocks
  const int nb2 = (bid & 7) * 64 + (bid >> 3);
  const int b = nb2 >> 7;
  const int q0 = ((nb2 >> 3) & 15) * 64, k0 = (nb2 & 7) * 128;
  const int qw = q0 + w * 16;                    // wave owns 16 q-rows
  size_t goff[4]; int lofs[4];
#pragma unroll
  for (int i = 0; i < 4; ++i) {
    int chunk = i * 4 + w;
    int row = chunk * 8 + (lane >> 3);
    int ss = (lane & 7) ^ (row & 7);
    goff[i] = (size_t)(k0 + row) * DHEAD + ss * 8;
    lofs[i] = chunk * 1024;
  }
  const bf16* Kb_b = Kb + (size_t)b * NHEADS * SEQ * DHEAD;
  const bf16* Qb_b = Qb + (size_t)b * NHEADS * SEQ * DHEAD;

  f32x4 macc[8] = {};
#pragma unroll
  for (int i = 0; i < 4; ++i) gll16(Kb_b + goff[i], sK + lofs[i]);
  asm volatile("s_waitcnt vmcnt(0)" ::: "memory");
  __syncthreads();

  for (int h = 0; h < NHEADS; ++h) {
    const int cur = (h & 1) << 14, nxt = cur ^ 16384;
    if (h + 1 < NHEADS) {
      const bf16* Kn = Kb_b + (size_t)(h + 1) * SEQ * DHEAD;
#pragma unroll
      for (int i = 0; i < 4; ++i) gll16(Kn + goff[i], sK + nxt + lofs[i]);
    }
    const bf16* Qbase = Qb_b + (size_t)h * SEQ * DHEAD;
    bf16x8 aq[2];
#pragma unroll
    for (int ks = 0; ks < 2; ++ks)
      aq[ks] = *(const bf16x8*)(Qbase + (size_t)(qw + (lane & 15)) * DHEAD
                                + ks * 32 + (lane >> 4) * 8);
    char* cK = sK + cur;
    f32x4 sc[8] = {};
#pragma unroll
    for (int ks = 0; ks < 2; ++ks)
#pragma unroll
      for (int ni = 0; ni < 8; ++ni) {
        bf16x8 bk = *(const bf16x8*)(cK + swz128(ni*16 + (lane & 15), ks*64 + (lane >> 4)*16));
        sc[ni] = __builtin_amdgcn_mfma_f32_16x16x32_bf16(aq[ks], bk, sc[ni], 0, 0, 0);
      }
    float lsc[4];
    const float* ls = lstat + ((size_t)(b * NHEADS + h)) * SEQ;
#pragma unroll
    for (int r = 0; r < 4; ++r)
      lsc[r] = 0.0625f * __builtin_amdgcn_rcpf(ls[qw + (lane >> 4)*4 + r]);
#pragma unroll
    for (int ni = 0; ni < 8; ++ni)
#pragma unroll
      for (int r = 0; r < 4; ++r)
        macc[ni][r] += __builtin_amdgcn_exp2f(sc[ni][r]) * lsc[r];
    asm volatile("s_waitcnt vmcnt(0)" ::: "memory");
    __syncthreads();
  }
#pragma unroll
  for (int r = 0; r < 4; ++r) {
    int qrow = qw + (lane >> 4) * 4 + r;
#pragma unroll
    for (int ni = 0; ni < 8; ++ni)
      out2[(size_t)(b * SEQ + qrow) * SEQ + k0 + ni * 16 + (lane & 15)] = macc[ni][r];
  }
}

// ---------------- residual LayerNorm (in-place on fp32 rows) ----------------
__global__ __launch_bounds__(256) void ln_kernel(
    float* __restrict__ hb, const float* __restrict__ g,
    const float* __restrict__ bvec, float* __restrict__ out)
{
  const int row = blockIdx.x, t = threadIdx.x;
  float4 v = *(const float4*)(hb + (size_t)row * DMODEL + t * 4);
  float s = v.x + v.y + v.z + v.w;
  float s2 = v.x*v.x + v.y*v.y + v.z*v.z + v.w*v.w;
#pragma unroll
  for (int off = 32; off >= 1; off >>= 1) {
    s  += __shfl_down(s, off);
    s2 += __shfl_down(s2, off);
  }
  __shared__ float red[8];
  const int w = t >> 6;
  if ((t & 63) == 0) { red[w] = s; red[4 + w] = s2; }
  __syncthreads();
  if (t == 0) {
    red[0] = red[0] + red[1] + red[2] + red[3];
    red[4] = red[4] + red[5] + red[6] + red[7];
  }
  __syncthreads();
  float mu = red[0] * (1.0f / DMODEL);
  float var = red[4] * (1.0f / DMODEL) - mu * mu;
  float rs = rsqrtf(var + 1e-5f);
  float4 gv = *(const float4*)(g + t * 4);
  float4 bv = *(const float4*)(bvec + t * 4);
  float4 o;
  o.x = (v.x - mu) * rs * gv.x + bv.x;
  o.y = (v.y - mu) * rs * gv.y + bv.y;
  o.z = (v.z - mu) * rs * gv.z + bv.z;
  o.w = (v.w - mu) * rs * gv.w + bv.w;
  *(float4*)(out + (size_t)row * DMODEL + t * 4) = o;
}

extern "C" void kernel_launch(void* const* d_in, const int* in_sizes, int n_in,
                              void* d_out, int out_size, void* d_ws, size_t ws_size,
                              hipStream_t stream) {
  (void)in_sizes; (void)n_in; (void)out_size; (void)ws_size;
  const float* x = (const float*)d_in[0];
  const float* w_[4]  = {(const float*)d_in[1],  (const float*)d_in[5],
                         (const float*)d_in[9],  (const float*)d_in[13]};
  const float* b_[4]  = {(const float*)d_in[2],  (const float*)d_in[6],
                         (const float*)d_in[10], (const float*)d_in[14]};
  const float* A_[4]  = {(const float*)d_in[3],  (const float*)d_in[7],
                         (const float*)d_in[11], (const float*)d_in[15]};
  const float* Bm_[4] = {(const float*)d_in[4],  (const float*)d_in[8],
                         (const float*)d_in[12], (const float*)d_in[16]};
  const float* lng = (const float*)d_in[17];
  const float* lnb = (const float*)d_in[18];

  char* ws = (char*)d_ws;
  bf16* xb    = (bf16*)(ws);                         // 8MB, reused as ctx later
  bf16* weff  = (bf16*)(ws + (8u  << 20));           // 4 x 2MB (q|k|v|o contiguous)
  bf16* Qb    = (bf16*)(ws + (16u << 20));           // 8MB [b][h][s][d] (pre-scaled)
  bf16* Kb    = (bf16*)(ws + (24u << 20));           // 8MB [b][h][s][d]
  bf16* Vb    = (bf16*)(ws + (32u << 20));           // 8MB [b][h][s][d]
  float* lstat = (float*)(ws + (40u << 20));         // 256KB
  bf16* ctx = xb;                    // alias: xb dead after QKV projections
  float* hbuf = (float*)d_out;       // fp32 scratch = output slot 0 (in-place LN)
  float* out2 = (float*)d_out + (size_t)MTOT * DMODEL;

  prep_weff_kernel<<<dim3(DMODEL, 4), dim3(256), 0, stream>>>(
      w_[0], A_[0], Bm_[0], w_[1], A_[1], Bm_[1],
      w_[2], A_[2], Bm_[2], w_[3], A_[3], Bm_[3], weff);
  cast_x_kernel<<<dim3(MTOT * DMODEL / 1024), dim3(256), 0, stream>>>(x, xb);

  gemm_qkv_kernel<<<dim3(384), 512, 0, stream>>>(
      xb, weff, b_[0], b_[1], b_[2], Qb, Kb, Vb);

  flash_kernel<<<dim3(512), 512, 0, stream>>>(Qb, Kb, Vb, ctx, lstat);
  mean_kernel<<<dim3(512), 256, 0, stream>>>(Qb, Kb, lstat, out2);
  gemm_o_kernel<<<dim3(512), 256, 0, stream>>>(
      ctx, weff + 3u * DMODEL * DMODEL, b_[3], x, hbuf);
  ln_kernel<<<dim3(MTOT), 256, 0, stream>>>(hbuf, lng, lnb, hbuf);
}

// Round 13
// 122.432 us; speedup vs baseline: 1.3209x; 1.1003x over previous
//
#include <hip/hip_runtime.h>

#define DMODEL 1024
#define NHEADS 16
#define DHEAD  64
#define RANK   16
#define BATCH  4
#define SEQ    1024
#define MTOT   (BATCH*SEQ)   // 4096
#define QSCALE 0.18033688011112042f  // log2(e)/8 : folded into Q projection

typedef __bf16 bf16;
typedef __bf16 bf16x8 __attribute__((ext_vector_type(8)));
typedef __bf16 bf16x4 __attribute__((ext_vector_type(4)));
typedef float  f32x4  __attribute__((ext_vector_type(4)));

// Byte-offset swizzle for LDS tiles with 128B rows (16B granules).
__device__ __forceinline__ int swz128(int row, int byte_in_row) {
  int slot = byte_in_row >> 4;
  return row * 128 + (((slot ^ (row & 7)) << 4) | (byte_in_row & 15));
}

// async global->LDS, 16B per lane. lds ptr wave-uniform; HW adds lane*16.
__device__ __forceinline__ void gll16(const void* g, void* l) {
  __builtin_amdgcn_global_load_lds((const __attribute__((address_space(1))) unsigned int*)g,
                                   (__attribute__((address_space(3))) unsigned int*)l, 16, 0, 0);
}

// two ds_read_b64_tr_b16 with literal offsets (rule 18 fence applied by caller)
#define TRRD(lo, hi, base, o0, o1)                                   \
  asm volatile("ds_read_b64_tr_b16 %0, %2 offset:" #o0 "\n\t"        \
               "ds_read_b64_tr_b16 %1, %2 offset:" #o1               \
               : "=v"(lo), "=v"(hi) : "v"(base));

// ------- fused prologue: blocks 0..4095 prep Weff, 4096..8191 cast x --------
__global__ void prep_kernel(
    const float* __restrict__ W0, const float* __restrict__ A0, const float* __restrict__ B0,
    const float* __restrict__ W1, const float* __restrict__ A1, const float* __restrict__ B1,
    const float* __restrict__ W2, const float* __restrict__ A2, const float* __restrict__ B2,
    const float* __restrict__ W3, const float* __restrict__ A3, const float* __restrict__ B3,
    bf16* __restrict__ out, const float* __restrict__ x, bf16* __restrict__ xb) {
  __shared__ float bsc[RANK];
  const int blk = blockIdx.x;
  if (blk < 4096) {
    const int l = blk >> 10;
    const float* W = l == 0 ? W0 : l == 1 ? W1 : l == 2 ? W2 : W3;
    const float* A = l == 0 ? A0 : l == 1 ? A1 : l == 2 ? A2 : A3;
    const float* Bm = l == 0 ? B0 : l == 1 ? B1 : l == 2 ? B2 : B3;
    bf16* o = out + (size_t)l * DMODEL * DMODEL;
    const int n = blk & 1023;
    if (threadIdx.x < RANK) bsc[threadIdx.x] = Bm[threadIdx.x * DMODEL + n] * 2.0f;
    __syncthreads();
    float br[RANK];
#pragma unroll
    for (int r = 0; r < RANK; ++r) br[r] = bsc[r];
    for (int k0 = 0; k0 < DMODEL; k0 += 256) {
      int k = k0 + threadIdx.x;
      float acc = W[n * DMODEL + k];
      const float4* arow = (const float4*)(A + k * RANK);
#pragma unroll
      for (int r4 = 0; r4 < 4; ++r4) {
        float4 a = arow[r4];
        acc += a.x*br[r4*4+0] + a.y*br[r4*4+1] + a.z*br[r4*4+2] + a.w*br[r4*4+3];
      }
      o[n * DMODEL + k] = (bf16)acc;
    }
  } else {
    int i = ((blk - 4096) * 256 + threadIdx.x) * 4;
    float4 v = *(const float4*)(x + i);
    bf16x4 o4 = { (bf16)v.x, (bf16)v.y, (bf16)v.z, (bf16)v.w };
    *(bf16x4*)(xb + i) = o4;
  }
}

// QKV fused over N=3072: 128x256 tile, 8 waves (2x4 grid, 64x64 per wave).
__global__ __launch_bounds__(512) void gemm_qkv_kernel(
    const bf16* __restrict__ xb, const bf16* __restrict__ weff,
    const float* __restrict__ bq, const float* __restrict__ bk, const float* __restrict__ bv,
    bf16* __restrict__ Qb, bf16* __restrict__ Kb, bf16* __restrict__ Vb)
{
  __shared__ __align__(16) char sA[16384];   // 128 rows x 64 bf16
  __shared__ __align__(16) char sB[32768];   // 256 rows x 64 bf16
  const int tid = threadIdx.x, w = tid >> 6, lane = tid & 63;
  const int bid = blockIdx.x;
  const int nb = (bid & 7) * 48 + (bid >> 3);
  const int n0 = (nb % 12) * 256, m0 = (nb / 12) * 128;
  const int z = n0 >> 10;
  const float* bias = z == 0 ? bq : z == 1 ? bk : bv;
  bf16* outp = z == 0 ? Qb : (z == 1 ? Kb : Vb);
  const float scl = z == 0 ? QSCALE : 1.0f;
  const int wm = (w & 1) * 64, wn = (w >> 1) * 64;
  f32x4 acc[4][4] = {};

  const bf16* pA[2]; const bf16* pB[4]; char* lA[2]; char* lB[4];
#pragma unroll
  for (int i = 0; i < 2; ++i) {
    int ci = i * 8 + w;
    int row = ci * 8 + (lane >> 3);
    int ss = (lane & 7) ^ (row & 7);
    pA[i] = xb + (size_t)(m0 + row) * DMODEL + ss * 8;
    lA[i] = sA + ci * 1024;
  }
#pragma unroll
  for (int i = 0; i < 4; ++i) {
    int ci = i * 8 + w;
    int row = ci * 8 + (lane >> 3);
    int ss = (lane & 7) ^ (row & 7);
    pB[i] = weff + (size_t)(n0 + row) * DMODEL + ss * 8;
    lB[i] = sB + ci * 1024;
  }
  for (int kt = 0; kt < DMODEL / 64; ++kt) {
    const int kbase = kt * 64;
#pragma unroll
    for (int i = 0; i < 2; ++i) gll16(pA[i] + kbase, lA[i]);
#pragma unroll
    for (int i = 0; i < 4; ++i) gll16(pB[i] + kbase, lB[i]);
    __syncthreads();
#pragma unroll
    for (int ks = 0; ks < 2; ++ks) {
      bf16x8 af[4], bfg[4];
#pragma unroll
      for (int mi = 0; mi < 4; ++mi)
        af[mi] = *(const bf16x8*)(sA + swz128(wm + mi*16 + (lane & 15), ks*64 + (lane >> 4)*16));
#pragma unroll
      for (int ni = 0; ni < 4; ++ni)
        bfg[ni] = *(const bf16x8*)(sB + swz128(wn + ni*16 + (lane & 15), ks*64 + (lane >> 4)*16));
#pragma unroll
      for (int mi = 0; mi < 4; ++mi)
#pragma unroll
        for (int ni = 0; ni < 4; ++ni)
          acc[mi][ni] = __builtin_amdgcn_mfma_f32_16x16x32_bf16(af[mi], bfg[ni], acc[mi][ni], 0, 0, 0);
    }
    __syncthreads();
  }

#pragma unroll
  for (int mi = 0; mi < 4; ++mi) {
#pragma unroll
    for (int ni = 0; ni < 4; ++ni) {
      int col = n0 + wn + ni * 16 + (lane & 15);
      float bcol = bias[col & 1023];
      int h = (col >> 6) & 15, d = col & 63;
#pragma unroll
      for (int r = 0; r < 4; ++r) {
        int row = m0 + wm + mi * 16 + (lane >> 4) * 4 + r;
        float v = (acc[mi][ni][r] + bcol) * scl;
        int b = row >> 10, s = row & 1023;
        outp[(size_t)((b * NHEADS + h) * SEQ + s) * DHEAD + d] = (bf16)v;
      }
    }
  }
}

// -------- flash attention: QBLK=128, 8 waves, K/V LDS double-buffer ---------
__global__ __launch_bounds__(512) void flash_kernel(
    const bf16* __restrict__ Qb, const bf16* __restrict__ Kb, const bf16* __restrict__ Vb,
    bf16* __restrict__ ctx, float* __restrict__ lstat)
{
  __shared__ __align__(16) char sK[2 * 8192];   // dbuf rows=key, cols=d (swizzled)
  __shared__ __align__(16) char sV[2 * 8192];   // dbuf subtiled [k/4][d/16][4][16]
  __shared__ __align__(16) char sP[8 * 2048];   // per-wave P^T [64 key][16 q]
  const int tid = threadIdx.x, w = tid >> 6, lane = tid & 63;
  const int bid = blockIdx.x;
  const int nb = (bid & 7) * 64 + (bid >> 3);
  const int bh = nb >> 3;
  const int q0 = (nb & 7) * 128;
  const bf16* Qbase = Qb + (size_t)bh * SEQ * DHEAD;
  const bf16* Kbase = Kb + (size_t)bh * SEQ * DHEAD;
  const bf16* Vbase = Vb + (size_t)bh * SEQ * DHEAD;
  const int qw = q0 + w * 16;

  bf16x8 aq[2];
#pragma unroll
  for (int ks = 0; ks < 2; ++ks)
    aq[ks] = *(const bf16x8*)(Qbase + (size_t)(qw + (lane & 15)) * DHEAD + ks * 32 + (lane >> 4) * 8);

  const bf16* pK; const bf16* pV; int lKo; int lVo;
  {
    int ci = w;
    int rowK = ci * 8 + (lane >> 3);
    int ssK = (lane & 7) ^ (rowK & 7);
    pK = Kbase + (size_t)rowK * DHEAD + ssK * 8;    // + kt*64*DHEAD
    lKo = ci * 1024;
    int kV = ci * 8 + ((lane >> 5) & 1) * 4 + ((lane >> 1) & 3);
    int dV = (((lane >> 3) & 3) << 4) + ((lane & 1) << 3);
    pV = Vbase + (size_t)kV * DHEAD + dV;           // + kt*64*DHEAD
    lVo = ci * 1024;
  }

  char* sPw = sP + w * 2048;
  const unsigned pbase = (unsigned)(uintptr_t)sPw + ((lane >> 4) << 8) + ((lane & 15) << 3);
  const unsigned vbase0 = (unsigned)(uintptr_t)sV + ((lane >> 4) << 10) + ((lane & 15) << 3);
  char* pwr = sPw + ((lane >> 4) << 3) + (lane & 15) * 32;

  f32x4 cacc[4] = {};
  float lsum[4] = {0.f, 0.f, 0.f, 0.f};

  // prologue: stage k-tile 0 into buffer 0
  gll16(pK, sK + lKo);
  gll16(pV, sV + lVo);
  __syncthreads();

  for (int kt = 0; kt < SEQ / 64; ++kt) {
    const int cur = (kt & 1) << 13, nxt = cur ^ 8192;
    if (kt + 1 < SEQ / 64) {       // prefetch next tile; drains at loop-end barrier
      const size_t kofs = (size_t)((kt + 1) * 64) * DHEAD;
      gll16(pK + kofs, sK + nxt + lKo);
      gll16(pV + kofs, sV + nxt + lVo);
    }

    f32x4 sc[4] = {};
    __builtin_amdgcn_s_setprio(1);
#pragma unroll
    for (int ks = 0; ks < 2; ++ks)
#pragma unroll
      for (int ni = 0; ni < 4; ++ni) {
        bf16x8 bk = *(const bf16x8*)(sK + cur + swz128(ni*16 + (lane & 15), ks*64 + (lane >> 4)*16));
        sc[ni] = __builtin_amdgcn_mfma_f32_16x16x32_bf16(aq[ks], bk, sc[ni], 0, 0, 0);
      }
    __builtin_amdgcn_s_setprio(0);

    // P = exp2(sc); accumulate row partial sums; write P^T [key][q]
#pragma unroll
    for (int ni = 0; ni < 4; ++ni) {
      float p0 = __builtin_amdgcn_exp2f(sc[ni][0]);
      float p1 = __builtin_amdgcn_exp2f(sc[ni][1]);
      float p2 = __builtin_amdgcn_exp2f(sc[ni][2]);
      float p3 = __builtin_amdgcn_exp2f(sc[ni][3]);
      lsum[0] += p0; lsum[1] += p1; lsum[2] += p2; lsum[3] += p3;
      bf16x4 pb = { (bf16)p0, (bf16)p1, (bf16)p2, (bf16)p3 };
      *(bf16x4*)(pwr + ni * 512) = pb;   // key=ni*16+(lane&15) -> *32B
    }
    asm volatile("s_waitcnt lgkmcnt(0)" ::: "memory");

    unsigned long long t0, t1, v0[4], v1[4];
    const unsigned vb = vbase0 + cur;
    // ks = 0
    TRRD(t0, t1, pbase, 0, 128)
    TRRD(v0[0], v1[0], vb, 0, 512)
    TRRD(v0[1], v1[1], vb, 128, 640)
    TRRD(v0[2], v1[2], vb, 256, 768)
    TRRD(v0[3], v1[3], vb, 384, 896)
    asm volatile("s_waitcnt lgkmcnt(0)" ::: "memory");
    __builtin_amdgcn_sched_barrier(0);
    {
      union { unsigned long long u[2]; bf16x8 v; } pu, vu;
      pu.u[0] = t0; pu.u[1] = t1;
      __builtin_amdgcn_s_setprio(1);
#pragma unroll
      for (int ni = 0; ni < 4; ++ni) {
        vu.u[0] = v0[ni]; vu.u[1] = v1[ni];
        cacc[ni] = __builtin_amdgcn_mfma_f32_16x16x32_bf16(pu.v, vu.v, cacc[ni], 0, 0, 0);
      }
      __builtin_amdgcn_s_setprio(0);
    }
    // ks = 1
    TRRD(t0, t1, pbase, 1024, 1152)
    TRRD(v0[0], v1[0], vb, 4096, 4608)
    TRRD(v0[1], v1[1], vb, 4224, 4736)
    TRRD(v0[2], v1[2], vb, 4352, 4864)
    TRRD(v0[3], v1[3], vb, 4480, 4992)
    asm volatile("s_waitcnt lgkmcnt(0)" ::: "memory");
    __builtin_amdgcn_sched_barrier(0);
    {
      union { unsigned long long u[2]; bf16x8 v; } pu, vu;
      pu.u[0] = t0; pu.u[1] = t1;
      __builtin_amdgcn_s_setprio(1);
#pragma unroll
      for (int ni = 0; ni < 4; ++ni) {
        vu.u[0] = v0[ni]; vu.u[1] = v1[ni];
        cacc[ni] = __builtin_amdgcn_mfma_f32_16x16x32_bf16(pu.v, vu.v, cacc[ni], 0, 0, 0);
      }
      __builtin_amdgcn_s_setprio(0);
    }
    __syncthreads();   // drains prefetch vmcnt + publishes next buffer
  }

  // one deferred row-sum reduce over the 16-lane group
#pragma unroll
  for (int r = 0; r < 4; ++r) {
#pragma unroll
    for (int off = 1; off < 16; off <<= 1) lsum[r] += __shfl_xor(lsum[r], off);
  }

  const int b = bh >> 4, hh = bh & 15;
#pragma unroll
  for (int r = 0; r < 4; ++r) {
    float inv = __builtin_amdgcn_rcpf(lsum[r]);
    int qrow = qw + (lane >> 4) * 4 + r;
#pragma unroll
    for (int ni = 0; ni < 4; ++ni) {
      int d = ni * 16 + (lane & 15);
      ctx[(size_t)(b * SEQ + qrow) * DMODEL + hh * DHEAD + d] = (bf16)(cacc[ni][r] * inv);
    }
    if ((lane & 15) == 0) lstat[(size_t)bh * SEQ + qrow] = lsum[r];
  }
}

// ------- fused tail: blocks 0..511 mean (64q x 128k, head-dbuf),           --
// -------             blocks 512..1023 gemm_o (64x128 + residual)           --
// Both are latency-bound at ~2 blocks/CU alone; co-scheduling interleaves
// their idle cycles. Shared 32KB LDS carve; block-uniform branch.
__global__ __launch_bounds__(256) void tail_kernel(
    const bf16* __restrict__ Qb, const bf16* __restrict__ Kb,
    const float* __restrict__ lstat, float* __restrict__ out2,
    const bf16* __restrict__ ctx, const bf16* __restrict__ weffo,
    const float* __restrict__ bias, const float* __restrict__ resid,
    float* __restrict__ outf)
{
  __shared__ __align__(16) char smem[2 * 16384];
  const int tid = threadIdx.x, w = tid >> 6, lane = tid & 63;

  if (blockIdx.x < 512) {
    // ---------------- mean path ----------------
    char* sK = smem;
    const int bid = blockIdx.x;
    const int nb2 = (bid & 7) * 64 + (bid >> 3);
    const int b = nb2 >> 7;
    const int q0 = ((nb2 >> 3) & 15) * 64, k0 = (nb2 & 7) * 128;
    const int qw = q0 + w * 16;
    size_t goff[4]; int lofs[4];
#pragma unroll
    for (int i = 0; i < 4; ++i) {
      int chunk = i * 4 + w;
      int row = chunk * 8 + (lane >> 3);
      int ss = (lane & 7) ^ (row & 7);
      goff[i] = (size_t)(k0 + row) * DHEAD + ss * 8;
      lofs[i] = chunk * 1024;
    }
    const bf16* Kb_b = Kb + (size_t)b * NHEADS * SEQ * DHEAD;
    const bf16* Qb_b = Qb + (size_t)b * NHEADS * SEQ * DHEAD;

    f32x4 macc[8] = {};
#pragma unroll
    for (int i = 0; i < 4; ++i) gll16(Kb_b + goff[i], sK + lofs[i]);
    asm volatile("s_waitcnt vmcnt(0)" ::: "memory");
    __syncthreads();

    for (int h = 0; h < NHEADS; ++h) {
      const int cur = (h & 1) << 14, nxt = cur ^ 16384;
      if (h + 1 < NHEADS) {
        const bf16* Kn = Kb_b + (size_t)(h + 1) * SEQ * DHEAD;
#pragma unroll
        for (int i = 0; i < 4; ++i) gll16(Kn + goff[i], sK + nxt + lofs[i]);
      }
      const bf16* Qbase = Qb_b + (size_t)h * SEQ * DHEAD;
      bf16x8 aq[2];
#pragma unroll
      for (int ks = 0; ks < 2; ++ks)
        aq[ks] = *(const bf16x8*)(Qbase + (size_t)(qw + (lane & 15)) * DHEAD
                                  + ks * 32 + (lane >> 4) * 8);
      char* cK = sK + cur;
      f32x4 sc[8] = {};
#pragma unroll
      for (int ks = 0; ks < 2; ++ks)
#pragma unroll
        for (int ni = 0; ni < 8; ++ni) {
          bf16x8 bk = *(const bf16x8*)(cK + swz128(ni*16 + (lane & 15), ks*64 + (lane >> 4)*16));
          sc[ni] = __builtin_amdgcn_mfma_f32_16x16x32_bf16(aq[ks], bk, sc[ni], 0, 0, 0);
        }
      float lsc[4];
      const float* ls = lstat + ((size_t)(b * NHEADS + h)) * SEQ;
#pragma unroll
      for (int r = 0; r < 4; ++r)
        lsc[r] = 0.0625f * __builtin_amdgcn_rcpf(ls[qw + (lane >> 4)*4 + r]);
#pragma unroll
      for (int ni = 0; ni < 8; ++ni)
#pragma unroll
        for (int r = 0; r < 4; ++r)
          macc[ni][r] += __builtin_amdgcn_exp2f(sc[ni][r]) * lsc[r];
      asm volatile("s_waitcnt vmcnt(0)" ::: "memory");
      __syncthreads();
    }
#pragma unroll
    for (int r = 0; r < 4; ++r) {
      int qrow = qw + (lane >> 4) * 4 + r;
#pragma unroll
      for (int ni = 0; ni < 8; ++ni)
        out2[(size_t)(b * SEQ + qrow) * SEQ + k0 + ni * 16 + (lane & 15)] = macc[ni][r];
    }
  } else {
    // ---------------- gemm_o path ----------------
    char* sA = smem; char* sB = smem + 8192;
    const int bid = blockIdx.x - 512;
    const int nb = (bid & 7) * 64 + (bid >> 3);
    const int n0 = (nb & 7) * 128, m0 = (nb >> 3) * 64;
    const int wm = (w & 1) * 32, wn = (w >> 1) * 64;
    f32x4 acc[2][4] = {};
    const bf16* pA[2]; char* lA[2];
    const bf16* pB[4]; char* lB[4];
#pragma unroll
    for (int i = 0; i < 2; ++i) {
      int chunk = i * 4 + w;
      int row = chunk * 8 + (lane >> 3);
      int ss = (lane & 7) ^ (row & 7);
      pA[i] = ctx + (size_t)(m0 + row) * DMODEL + ss * 8;
      lA[i] = sA + chunk * 1024;
    }
#pragma unroll
    for (int i = 0; i < 4; ++i) {
      int chunk = i * 4 + w;
      int row = chunk * 8 + (lane >> 3);
      int ss = (lane & 7) ^ (row & 7);
      pB[i] = weffo + (size_t)(n0 + row) * DMODEL + ss * 8;
      lB[i] = sB + chunk * 1024;
    }
    for (int kt = 0; kt < DMODEL / 64; ++kt) {
      const int kbase = kt * 64;
#pragma unroll
      for (int i = 0; i < 2; ++i) gll16(pA[i] + kbase, lA[i]);
#pragma unroll
      for (int i = 0; i < 4; ++i) gll16(pB[i] + kbase, lB[i]);
      __syncthreads();
#pragma unroll
      for (int ks = 0; ks < 2; ++ks) {
        bf16x8 af[2], bfg[4];
#pragma unroll
        for (int mi = 0; mi < 2; ++mi)
          af[mi] = *(const bf16x8*)(sA + swz128(wm + mi*16 + (lane & 15), ks*64 + (lane >> 4)*16));
#pragma unroll
        for (int ni = 0; ni < 4; ++ni)
          bfg[ni] = *(const bf16x8*)(sB + swz128(wn + ni*16 + (lane & 15), ks*64 + (lane >> 4)*16));
#pragma unroll
        for (int mi = 0; mi < 2; ++mi)
#pragma unroll
          for (int ni = 0; ni < 4; ++ni)
            acc[mi][ni] = __builtin_amdgcn_mfma_f32_16x16x32_bf16(af[mi], bfg[ni], acc[mi][ni], 0, 0, 0);
      }
      __syncthreads();
    }
#pragma unroll
    for (int mi = 0; mi < 2; ++mi) {
#pragma unroll
      for (int ni = 0; ni < 4; ++ni) {
        int col = n0 + wn + ni * 16 + (lane & 15);
        float bcol = bias[col];
#pragma unroll
        for (int r = 0; r < 4; ++r) {
          int row = m0 + wm + mi * 16 + (lane >> 4) * 4 + r;
          outf[(size_t)row * DMODEL + col] =
              acc[mi][ni][r] + bcol + resid[(size_t)row * DMODEL + col];
        }
      }
    }
  }
}

// ---------------- residual LayerNorm (in-place on fp32 rows) ----------------
__global__ __launch_bounds__(256) void ln_kernel(
    float* __restrict__ hb, const float* __restrict__ g,
    const float* __restrict__ bvec, float* __restrict__ out)
{
  const int row = blockIdx.x, t = threadIdx.x;
  float4 v = *(const float4*)(hb + (size_t)row * DMODEL + t * 4);
  float s = v.x + v.y + v.z + v.w;
  float s2 = v.x*v.x + v.y*v.y + v.z*v.z + v.w*v.w;
#pragma unroll
  for (int off = 32; off >= 1; off >>= 1) {
    s  += __shfl_down(s, off);
    s2 += __shfl_down(s2, off);
  }
  __shared__ float red[8];
  const int w = t >> 6;
  if ((t & 63) == 0) { red[w] = s; red[4 + w] = s2; }
  __syncthreads();
  if (t == 0) {
    red[0] = red[0] + red[1] + red[2] + red[3];
    red[4] = red[4] + red[5] + red[6] + red[7];
  }
  __syncthreads();
  float mu = red[0] * (1.0f / DMODEL);
  float var = red[4] * (1.0f / DMODEL) - mu * mu;
  float rs = rsqrtf(var + 1e-5f);
  float4 gv = *(const float4*)(g + t * 4);
  float4 bv = *(const float4*)(bvec + t * 4);
  float4 o;
  o.x = (v.x - mu) * rs * gv.x + bv.x;
  o.y = (v.y - mu) * rs * gv.y + bv.y;
  o.z = (v.z - mu) * rs * gv.z + bv.z;
  o.w = (v.w - mu) * rs * gv.w + bv.w;
  *(float4*)(out + (size_t)row * DMODEL + t * 4) = o;
}

extern "C" void kernel_launch(void* const* d_in, const int* in_sizes, int n_in,
                              void* d_out, int out_size, void* d_ws, size_t ws_size,
                              hipStream_t stream) {
  (void)in_sizes; (void)n_in; (void)out_size; (void)ws_size;
  const float* x = (const float*)d_in[0];
  const float* w_[4]  = {(const float*)d_in[1],  (const float*)d_in[5],
                         (const float*)d_in[9],  (const float*)d_in[13]};
  const float* b_[4]  = {(const float*)d_in[2],  (const float*)d_in[6],
                         (const float*)d_in[10], (const float*)d_in[14]};
  const float* A_[4]  = {(const float*)d_in[3],  (const float*)d_in[7],
                         (const float*)d_in[11], (const float*)d_in[15]};
  const float* Bm_[4] = {(const float*)d_in[4],  (const float*)d_in[8],
                         (const float*)d_in[12], (const float*)d_in[16]};
  const float* lng = (const float*)d_in[17];
  const float* lnb = (const float*)d_in[18];

  char* ws = (char*)d_ws;
  bf16* xb    = (bf16*)(ws);                         // 8MB, reused as ctx later
  bf16* weff  = (bf16*)(ws + (8u  << 20));           // 4 x 2MB (q|k|v|o contiguous)
  bf16* Qb    = (bf16*)(ws + (16u << 20));           // 8MB [b][h][s][d] (pre-scaled)
  bf16* Kb    = (bf16*)(ws + (24u << 20));           // 8MB [b][h][s][d]
  bf16* Vb    = (bf16*)(ws + (32u << 20));           // 8MB [b][h][s][d]
  float* lstat = (float*)(ws + (40u << 20));         // 256KB
  bf16* ctx = xb;                    // alias: xb dead after QKV projections
  float* hbuf = (float*)d_out;       // fp32 scratch = output slot 0 (in-place LN)
  float* out2 = (float*)d_out + (size_t)MTOT * DMODEL;

  prep_kernel<<<dim3(8192), dim3(256), 0, stream>>>(
      w_[0], A_[0], Bm_[0], w_[1], A_[1], Bm_[1],
      w_[2], A_[2], Bm_[2], w_[3], A_[3], Bm_[3], weff, x, xb);

  gemm_qkv_kernel<<<dim3(384), 512, 0, stream>>>(
      xb, weff, b_[0], b_[1], b_[2], Qb, Kb, Vb);

  flash_kernel<<<dim3(512), 512, 0, stream>>>(Qb, Kb, Vb, ctx, lstat);

  tail_kernel<<<dim3(1024), 256, 0, stream>>>(
      Qb, Kb, lstat, out2,
      ctx, weff + 3u * DMODEL * DMODEL, b_[3], x, hbuf);

  ln_kernel<<<dim3(MTOT), 256, 0, stream>>>(hbuf, lng, lnb, hbuf);
}